// Round 1
// baseline (1000.529 us; speedup 1.0000x reference)
//
#include <hip/hip_runtime.h>
#include <hip/hip_bf16.h>

// Problem constants (match reference setup_inputs)
#define BG   128          // graphs
#define NPG  1000         // nodes per graph
#define EPG  16000        // edges per graph
#define DIM  128          // feature dim
#define KCL  64           // clusters (only appears as 1/K scale)
#define CCL  10           // classes
#define NN   (BG*NPG)     // 128000 nodes
#define EE   (BG*EPG)     // 2048000 edges

// ---------------- CSR build ----------------

__global__ __launch_bounds__(256) void count_k(const int* __restrict__ dst, int* __restrict__ cnt) {
    int e = blockIdx.x * 256 + threadIdx.x;
    if (e < EE) atomicAdd(&cnt[dst[e]], 1);
}

__global__ __launch_bounds__(256) void dinv_k(const int* __restrict__ cnt, float* __restrict__ dinv) {
    int n = blockIdx.x * 256 + threadIdx.x;
    if (n < NN) dinv[n] = rsqrtf((float)(cnt[n] + 1));   // +1 self-loop
}

// Per-graph exclusive scan of in-degree counts -> CSR offsets.
// One block per graph (1000 counts, exactly EPG total edges per graph).
__global__ __launch_bounds__(256) void scan_k(const int* __restrict__ cnt, int* __restrict__ offs) {
    int b = blockIdx.x;
    const int nbase = b * NPG;
    const int ebase = b * EPG;
    __shared__ int sdata[256];
    int running = 0;
    for (int j = 0; j < 4; ++j) {
        int i = j * 256 + threadIdx.x;
        int v = (i < NPG) ? cnt[nbase + i] : 0;
        int x = v;
        sdata[threadIdx.x] = x;
        __syncthreads();
        for (int off = 1; off < 256; off <<= 1) {
            int y = (threadIdx.x >= off) ? sdata[threadIdx.x - off] : 0;
            __syncthreads();
            x += y;
            sdata[threadIdx.x] = x;
            __syncthreads();
        }
        int excl = x - v;
        if (i < NPG) offs[nbase + i] = ebase + running + excl;
        int total = sdata[255];
        __syncthreads();   // protect sdata before next round
        running += total;
    }
}

__global__ __launch_bounds__(256) void fill_k(const int* __restrict__ src, const int* __restrict__ dst,
                                              const int* __restrict__ offs, int* __restrict__ fill,
                                              int* __restrict__ bucket) {
    int e = blockIdx.x * 256 + threadIdx.x;
    if (e < EE) {
        int d = dst[e];
        int p = atomicAdd(&fill[d], 1);
        bucket[offs[d] + p] = src[e];
    }
}

// ---------------- GEMM: out[N,128] = A[N,128] @ W[128,128] ----------------
// W staged in (dynamic) LDS; 4 waves/block, 4 rows/wave -> 16 rows/block.
__global__ __launch_bounds__(256) void gemm128_k(const float* __restrict__ A, const float* __restrict__ W,
                                                 float* __restrict__ out) {
    extern __shared__ float Ws[];   // 128*128 floats = 64 KiB
    for (int i = threadIdx.x; i < DIM * DIM / 4; i += 256)
        ((float4*)Ws)[i] = ((const float4*)W)[i];
    __syncthreads();

    int wave = threadIdx.x >> 6;
    int lane = threadIdx.x & 63;
    int row0 = blockIdx.x * 16 + wave * 4;
    const float* a0 = A + (size_t)row0 * DIM;
    int c = lane * 2;

    float2 acc0 = {0.f, 0.f}, acc1 = {0.f, 0.f}, acc2 = {0.f, 0.f}, acc3 = {0.f, 0.f};
#pragma unroll 8
    for (int d = 0; d < DIM; ++d) {
        float2 w = *(const float2*)&Ws[d * DIM + c];
        float x0 = a0[d];
        float x1 = a0[DIM + d];
        float x2 = a0[2 * DIM + d];
        float x3 = a0[3 * DIM + d];
        acc0.x += x0 * w.x; acc0.y += x0 * w.y;
        acc1.x += x1 * w.x; acc1.y += x1 * w.y;
        acc2.x += x2 * w.x; acc2.y += x2 * w.y;
        acc3.x += x3 * w.x; acc3.y += x3 * w.y;
    }
    float* o0 = out + (size_t)row0 * DIM;
    *(float2*)&o0[c]            = acc0;
    *(float2*)&o0[DIM + c]      = acc1;
    *(float2*)&o0[2 * DIM + c]  = acc2;
    *(float2*)&o0[3 * DIM + c]  = acc3;
}

// ---------------- GCN aggregation (gather over CSR) ----------------
// out[n] = relu( dinv[n]*sum_{s in in(n)} dinv[s]*xw[s] + dinv[n]^2*xw[n] + bias )
// POOL=true: instead of writing out, block-reduce and atomicAdd into pooled[graph].
template <bool POOL>
__global__ __launch_bounds__(256) void agg_k(const float* __restrict__ xw, const float* __restrict__ dinv,
                                             const int* __restrict__ offs, const int* __restrict__ cnt,
                                             const int* __restrict__ bucket, const float* __restrict__ bias,
                                             float* __restrict__ out, float* __restrict__ pooled) {
    __shared__ float red[4][DIM];
    int wave = threadIdx.x >> 6;
    int lane = threadIdx.x & 63;
    int n = blockIdx.x * 4 + wave;      // grid = NN/4, exact
    int c = lane * 2;

    float di = dinv[n];
    int o = offs[n];
    int m = cnt[n];

    float ax = 0.f, ay = 0.f;
    for (int j = 0; j < m; ++j) {
        int s = bucket[o + j];          // wave-uniform broadcast load
        float w = dinv[s];
        float2 v = *(const float2*)&xw[(size_t)s * DIM + c];
        ax += w * v.x;
        ay += w * v.y;
    }
    float2 vs = *(const float2*)&xw[(size_t)n * DIM + c];
    float rx = fmaxf(di * ax + di * di * vs.x + bias[c], 0.f);
    float ry = fmaxf(di * ay + di * di * vs.y + bias[c + 1], 0.f);

    if (!POOL) {
        *(float2*)&out[(size_t)n * DIM + c] = make_float2(rx, ry);
    } else {
        red[wave][c] = rx;
        red[wave][c + 1] = ry;
        __syncthreads();
        if (threadIdx.x < DIM) {
            int d = threadIdx.x;
            float s4 = red[0][d] + red[1][d] + red[2][d] + red[3][d];
            int b = blockIdx.x / (NPG / 4);     // 250 blocks per graph, exact
            atomicAdd(&pooled[b * DIM + d], s4);
        }
    }
}

// ---------------- Final MLP head ----------------
// out[g] = relu(pooled[g]*(1/K) @ W1 + b1) @ W2 + b2
__global__ __launch_bounds__(128) void mlp_k(const float* __restrict__ pooled,
                                             const float* __restrict__ W1, const float* __restrict__ b1,
                                             const float* __restrict__ W2, const float* __restrict__ b2,
                                             float* __restrict__ out) {
    int g = blockIdx.x;
    int t = threadIdx.x;
    __shared__ float prow[DIM];
    __shared__ float o1[DIM];
    prow[t] = pooled[g * DIM + t] * (1.0f / (float)KCL);
    __syncthreads();
    float acc = b1[t];
#pragma unroll 8
    for (int d = 0; d < DIM; ++d) acc += prow[d] * W1[d * DIM + t];
    o1[t] = fmaxf(acc, 0.f);
    __syncthreads();
    if (t < CCL) {
        float a = b2[t];
#pragma unroll 8
        for (int cc = 0; cc < DIM; ++cc) a += o1[cc] * W2[cc * CCL + t];
        out[g * CCL + t] = a;
    }
}

extern "C" void kernel_launch(void* const* d_in, const int* in_sizes, int n_in,
                              void* d_out, int out_size, void* d_ws, size_t ws_size,
                              hipStream_t stream) {
    const float* x     = (const float*)d_in[0];
    const int*   ei    = (const int*)d_in[1];      // [2, E]: src then dst
    const float* W_pre = (const float*)d_in[3];
    const float* b_pre = (const float*)d_in[4];
    const float* W_emb = (const float*)d_in[5];
    const float* b_emb = (const float*)d_in[6];
    // d_in[7]/d_in[8] (W_asn/b_asn) provably unused: softmax rows sum to 1
    const float* W1    = (const float*)d_in[9];
    const float* b1    = (const float*)d_in[10];
    const float* W2    = (const float*)d_in[11];
    const float* b2    = (const float*)d_in[12];
    float* out = (float*)d_out;

    const int* srcp = ei;
    const int* dstp = ei + EE;

    // workspace layout (all 256B-aligned by construction)
    char* ws = (char*)d_ws;
    size_t off = 0;
    int*   cnt    = (int*)(ws + off);  off += (size_t)NN * 4;        // 512000
    int*   fill   = (int*)(ws + off);  off += (size_t)NN * 4;
    float* dinv   = (float*)(ws + off); off += (size_t)NN * 4;
    int*   offs   = (int*)(ws + off);  off += (size_t)NN * 4;
    float* pooled = (float*)(ws + off); off += (size_t)BG * DIM * 4; // 65536
    int*   bucket = (int*)(ws + off);  off += (size_t)EE * 4;        // 8.192 MB
    float* xw     = (float*)(ws + off); off += (size_t)NN * DIM * 4; // 65.536 MB
    float* h      = (float*)(ws + off); off += (size_t)NN * DIM * 4; // 65.536 MB
    if (ws_size < off) return;  // fail loudly (output stays poisoned)

    hipMemsetAsync(cnt, 0, (size_t)NN * 4, stream);
    hipMemsetAsync(fill, 0, (size_t)NN * 4, stream);
    hipMemsetAsync(pooled, 0, (size_t)BG * DIM * 4, stream);

    count_k<<<(EE + 255) / 256, 256, 0, stream>>>(dstp, cnt);
    dinv_k<<<(NN + 255) / 256, 256, 0, stream>>>(cnt, dinv);
    scan_k<<<BG, 256, 0, stream>>>(cnt, offs);
    fill_k<<<(EE + 255) / 256, 256, 0, stream>>>(srcp, dstp, offs, fill, bucket);

    // conv1: h = relu(agg(x @ W_pre) + b_pre)
    gemm128_k<<<NN / 16, 256, 65536, stream>>>(x, W_pre, xw);
    agg_k<false><<<NN / 4, 256, 0, stream>>>(xw, dinv, offs, cnt, bucket, b_pre, h, nullptr);

    // conv2: NE = relu(agg(h @ W_emb) + b_emb), fused pool: pooled[b] += NE[n]
    gemm128_k<<<NN / 16, 256, 65536, stream>>>(h, W_emb, xw);
    agg_k<true><<<NN / 4, 256, 0, stream>>>(xw, dinv, offs, cnt, bucket, b_emb, nullptr, pooled);

    // head
    mlp_k<<<BG, 128, 0, stream>>>(pooled, W1, b1, W2, b2, out);
}

// Round 2
// 604.673 us; speedup vs baseline: 1.6547x; 1.6547x over previous
//
#include <hip/hip_runtime.h>
#include <hip/hip_bf16.h>

// Problem constants (match reference setup_inputs)
#define BG   128          // graphs
#define NPG  1000         // nodes per graph
#define EPG  16000        // edges per graph
#define DIM  128          // feature dim
#define KCL  64           // clusters (only appears as 1/K scale)
#define CCL  10           // classes
#define NN   (BG*NPG)     // 128000 nodes
#define EE   (BG*EPG)     // 2048000 edges
#define GR   64           // gemm rows per block

// ---------------- CSR build ----------------

__global__ __launch_bounds__(256) void count_k(const int* __restrict__ dst, int* __restrict__ cnt) {
    int e = blockIdx.x * 256 + threadIdx.x;
    if (e < EE) atomicAdd(&cnt[dst[e]], 1);
}

__global__ __launch_bounds__(256) void dinv_k(const int* __restrict__ cnt, float* __restrict__ dinv) {
    int n = blockIdx.x * 256 + threadIdx.x;
    if (n < NN) dinv[n] = rsqrtf((float)(cnt[n] + 1));   // +1 self-loop
}

// Per-graph exclusive scan of in-degree counts -> CSR offsets (1 block/graph).
__global__ __launch_bounds__(256) void scan_k(const int* __restrict__ cnt, int* __restrict__ offs) {
    int b = blockIdx.x;
    const int nbase = b * NPG;
    const int ebase = b * EPG;
    __shared__ int sdata[256];
    int running = 0;
    for (int j = 0; j < 4; ++j) {
        int i = j * 256 + threadIdx.x;
        int v = (i < NPG) ? cnt[nbase + i] : 0;
        int x = v;
        sdata[threadIdx.x] = x;
        __syncthreads();
        for (int off = 1; off < 256; off <<= 1) {
            int y = (threadIdx.x >= off) ? sdata[threadIdx.x - off] : 0;
            __syncthreads();
            x += y;
            sdata[threadIdx.x] = x;
            __syncthreads();
        }
        int excl = x - v;
        if (i < NPG) offs[nbase + i] = ebase + running + excl;
        int total = sdata[255];
        __syncthreads();
        running += total;
    }
}

__global__ __launch_bounds__(256) void fill_k(const int* __restrict__ src, const int* __restrict__ dst,
                                              const int* __restrict__ offs, int* __restrict__ fill,
                                              int* __restrict__ bucket) {
    int e = blockIdx.x * 256 + threadIdx.x;
    if (e < EE) {
        int d = dst[e];
        int p = atomicAdd(&fill[d], 1);
        bucket[offs[d] + p] = src[e];
    }
}

// ---------------- GEMM: out[n] = dinv[n] * (A[n] @ W), A tile in LDS ----------------
// 256 threads = 4 waves, 64 rows/block (16/wave), W streamed from L2 (64 KB, resident).
__global__ __launch_bounds__(256) void gemm128_k(const float* __restrict__ A, const float* __restrict__ W,
                                                 const float* __restrict__ dinv, float* __restrict__ out) {
    __shared__ float As[GR * DIM];    // 32 KiB
    const float* a = A + (size_t)blockIdx.x * GR * DIM;
    for (int i = threadIdx.x; i < GR * DIM / 4; i += 256)
        ((float4*)As)[i] = ((const float4*)a)[i];
    __syncthreads();

    int wave = threadIdx.x >> 6, lane = threadIdx.x & 63;
    int r0 = wave * 16;
    int c = lane * 2;

    float accx[16], accy[16];
#pragma unroll
    for (int r = 0; r < 16; ++r) { accx[r] = 0.f; accy[r] = 0.f; }

    for (int d0 = 0; d0 < DIM; d0 += 4) {
        float2 w0 = *(const float2*)&W[(d0 + 0) * DIM + c];
        float2 w1 = *(const float2*)&W[(d0 + 1) * DIM + c];
        float2 w2 = *(const float2*)&W[(d0 + 2) * DIM + c];
        float2 w3 = *(const float2*)&W[(d0 + 3) * DIM + c];
#pragma unroll
        for (int r = 0; r < 16; ++r) {
            float4 av = *(const float4*)&As[(r0 + r) * DIM + d0];  // broadcast ds_read_b128
            accx[r] += av.x * w0.x + av.y * w1.x + av.z * w2.x + av.w * w3.x;
            accy[r] += av.x * w0.y + av.y * w1.y + av.z * w2.y + av.w * w3.y;
        }
    }

    int rowb = blockIdx.x * GR + r0;
#pragma unroll
    for (int r = 0; r < 16; ++r) {
        float sc = dinv[rowb + r];
        *(float2*)&out[(size_t)(rowb + r) * DIM + c] = make_float2(accx[r] * sc, accy[r] * sc);
    }
}

// ---------------- GCN aggregation over CSR ----------------
// xws rows are pre-scaled by dinv: out[n] = relu( dinv[n]*(sum_in xws[s] + xws[n]) + bias )
// XCD swizzle: graph g -> XCD g%8, so each XCD's gather working set is one graph slice (L2-resident).
template <bool POOL>
__global__ __launch_bounds__(256) void agg_k(const float* __restrict__ xws, const float* __restrict__ dinv,
                                             const int* __restrict__ offs, const int* __restrict__ cnt,
                                             const int* __restrict__ bucket, const float* __restrict__ bias,
                                             float* __restrict__ out, float* __restrict__ pooled) {
    __shared__ float red[4][DIM];
    int p = blockIdx.x;              // 32000 = 8 XCDs * 16 graphs * 250 blocks
    int xcd = p & 7;
    int j = p >> 3;
    int g = xcd + 8 * (j / 250);
    int blk = j - 250 * (j / 250);
    int wave = threadIdx.x >> 6, lane = threadIdx.x & 63;
    int n = __builtin_amdgcn_readfirstlane(g * NPG + blk * 4 + wave);
    int c = lane * 2;

    float di = dinv[n];
    int o = __builtin_amdgcn_readfirstlane(offs[n]);
    int m = __builtin_amdgcn_readfirstlane(cnt[n]);
    const float2* base = (const float2*)xws;

    float ax = 0.f, ay = 0.f;
    int jj = 0;
    for (; jj + 4 <= m; jj += 4) {
        int s0 = bucket[o + jj];
        int s1 = bucket[o + jj + 1];
        int s2 = bucket[o + jj + 2];
        int s3 = bucket[o + jj + 3];
        float2 v0 = base[(size_t)s0 * 64 + lane];
        float2 v1 = base[(size_t)s1 * 64 + lane];
        float2 v2 = base[(size_t)s2 * 64 + lane];
        float2 v3 = base[(size_t)s3 * 64 + lane];
        ax += (v0.x + v1.x) + (v2.x + v3.x);
        ay += (v0.y + v1.y) + (v2.y + v3.y);
    }
    for (; jj < m; ++jj) {
        int s = bucket[o + jj];
        float2 v = base[(size_t)s * 64 + lane];
        ax += v.x; ay += v.y;
    }

    float2 vs = base[(size_t)n * 64 + lane];
    float2 bb = *(const float2*)&bias[c];
    float rx = fmaxf(di * (ax + vs.x) + bb.x, 0.f);
    float ry = fmaxf(di * (ay + vs.y) + bb.y, 0.f);

    if (!POOL) {
        *(float2*)&out[(size_t)n * DIM + c] = make_float2(rx, ry);
    } else {
        red[wave][c] = rx;
        red[wave][c + 1] = ry;
        __syncthreads();
        if (threadIdx.x < DIM) {
            int d = threadIdx.x;
            float s4 = red[0][d] + red[1][d] + red[2][d] + red[3][d];
            atomicAdd(&pooled[g * DIM + d], s4);
        }
    }
}

// ---------------- Final MLP head ----------------
__global__ __launch_bounds__(128) void mlp_k(const float* __restrict__ pooled,
                                             const float* __restrict__ W1, const float* __restrict__ b1,
                                             const float* __restrict__ W2, const float* __restrict__ b2,
                                             float* __restrict__ out) {
    int g = blockIdx.x;
    int t = threadIdx.x;
    __shared__ float prow[DIM];
    __shared__ float o1[DIM];
    prow[t] = pooled[g * DIM + t] * (1.0f / (float)KCL);
    __syncthreads();
    float acc = b1[t];
#pragma unroll 8
    for (int d = 0; d < DIM; ++d) acc += prow[d] * W1[d * DIM + t];
    o1[t] = fmaxf(acc, 0.f);
    __syncthreads();
    if (t < CCL) {
        float a = b2[t];
#pragma unroll 8
        for (int cc = 0; cc < DIM; ++cc) a += o1[cc] * W2[cc * CCL + t];
        out[g * CCL + t] = a;
    }
}

extern "C" void kernel_launch(void* const* d_in, const int* in_sizes, int n_in,
                              void* d_out, int out_size, void* d_ws, size_t ws_size,
                              hipStream_t stream) {
    const float* x     = (const float*)d_in[0];
    const int*   ei    = (const int*)d_in[1];      // [2, E]: src then dst
    const float* W_pre = (const float*)d_in[3];
    const float* b_pre = (const float*)d_in[4];
    const float* W_emb = (const float*)d_in[5];
    const float* b_emb = (const float*)d_in[6];
    // W_asn/b_asn provably unused: softmax rows sum to 1, S^T A S unused
    const float* W1    = (const float*)d_in[9];
    const float* b1    = (const float*)d_in[10];
    const float* W2    = (const float*)d_in[11];
    const float* b2    = (const float*)d_in[12];
    float* out = (float*)d_out;

    const int* srcp = ei;
    const int* dstp = ei + EE;

    char* ws = (char*)d_ws;
    size_t off = 0;
    int*   cnt    = (int*)(ws + off);   off += (size_t)NN * 4;
    int*   fill   = (int*)(ws + off);   off += (size_t)NN * 4;
    float* dinv   = (float*)(ws + off); off += (size_t)NN * 4;
    int*   offs   = (int*)(ws + off);   off += (size_t)NN * 4;
    float* pooled = (float*)(ws + off); off += (size_t)BG * DIM * 4;
    int*   bucket = (int*)(ws + off);   off += (size_t)EE * 4;
    float* xws    = (float*)(ws + off); off += (size_t)NN * DIM * 4;
    float* h      = (float*)(ws + off); off += (size_t)NN * DIM * 4;
    if (ws_size < off) return;

    hipMemsetAsync(cnt, 0, (size_t)NN * 4, stream);
    hipMemsetAsync(fill, 0, (size_t)NN * 4, stream);
    hipMemsetAsync(pooled, 0, (size_t)BG * DIM * 4, stream);

    count_k<<<(EE + 255) / 256, 256, 0, stream>>>(dstp, cnt);
    dinv_k<<<(NN + 255) / 256, 256, 0, stream>>>(cnt, dinv);
    scan_k<<<BG, 256, 0, stream>>>(cnt, offs);
    fill_k<<<(EE + 255) / 256, 256, 0, stream>>>(srcp, dstp, offs, fill, bucket);

    // conv1: xws = dinv * (x @ W_pre); h = relu(dinv*(gather-sum + self) + b_pre)
    gemm128_k<<<NN / GR, 256, 0, stream>>>(x, W_pre, dinv, xws);
    agg_k<false><<<NN / 4, 256, 0, stream>>>(xws, dinv, offs, cnt, bucket, b_pre, h, nullptr);

    // conv2 + fused mean-pool numerator
    gemm128_k<<<NN / GR, 256, 0, stream>>>(h, W_emb, dinv, xws);
    agg_k<true><<<NN / 4, 256, 0, stream>>>(xws, dinv, offs, cnt, bucket, b_emb, nullptr, pooled);

    mlp_k<<<BG, 128, 0, stream>>>(pooled, W1, b1, W2, b2, out);
}

// Round 4
// 516.570 us; speedup vs baseline: 1.9369x; 1.1706x over previous
//
#include <hip/hip_runtime.h>
#include <hip/hip_bf16.h>

// Problem constants (match reference setup_inputs)
#define BG   128          // graphs
#define NPG  1000         // nodes per graph
#define EPG  16000        // edges per graph
#define DIM  128          // feature dim
#define KCL  64           // clusters (only appears as 1/K scale)
#define CCL  10           // classes
#define NN   (BG*NPG)     // 128000 nodes
#define EE   (BG*EPG)     // 2048000 edges

typedef __attribute__((ext_vector_type(8))) short bf16x8;
typedef __attribute__((ext_vector_type(4))) float f32x4;

__device__ __forceinline__ ushort f2bf(float x) {       // RNE fp32->bf16
    unsigned u = __float_as_uint(x);
    return (ushort)((u + 0x7fffu + ((u >> 16) & 1u)) >> 16);
}
__device__ __forceinline__ float bf2f(ushort h) { return __uint_as_float(((unsigned)h) << 16); }

// ---------------- CSR build ----------------

__global__ __launch_bounds__(256) void count_k(const int* __restrict__ dst, int* __restrict__ cnt) {
    int e = blockIdx.x * 256 + threadIdx.x;
    if (e < EE) atomicAdd(&cnt[dst[e]], 1);
}

__global__ __launch_bounds__(256) void dinv_k(const int* __restrict__ cnt, float* __restrict__ dinv) {
    int n = blockIdx.x * 256 + threadIdx.x;
    if (n < NN) dinv[n] = rsqrtf((float)(cnt[n] + 1));   // +1 self-loop
}

// Per-graph exclusive scan of in-degree counts -> CSR offsets (1 block/graph).
__global__ __launch_bounds__(256) void scan_k(const int* __restrict__ cnt, int* __restrict__ offs) {
    int b = blockIdx.x;
    const int nbase = b * NPG;
    const int ebase = b * EPG;
    __shared__ int sdata[256];
    int running = 0;
    for (int j = 0; j < 4; ++j) {
        int i = j * 256 + threadIdx.x;
        int v = (i < NPG) ? cnt[nbase + i] : 0;
        int x = v;
        sdata[threadIdx.x] = x;
        __syncthreads();
        for (int off = 1; off < 256; off <<= 1) {
            int y = (threadIdx.x >= off) ? sdata[threadIdx.x - off] : 0;
            __syncthreads();
            x += y;
            sdata[threadIdx.x] = x;
            __syncthreads();
        }
        int excl = x - v;
        if (i < NPG) offs[nbase + i] = ebase + running + excl;
        int total = sdata[255];
        __syncthreads();
        running += total;
    }
}

__global__ __launch_bounds__(256) void fill_k(const int* __restrict__ src, const int* __restrict__ dst,
                                              const int* __restrict__ offs, int* __restrict__ fill,
                                              int* __restrict__ bucket) {
    int e = blockIdx.x * 256 + threadIdx.x;
    if (e < EE) {
        int d = dst[e];
        int p = atomicAdd(&fill[d], 1);
        bucket[offs[d] + p] = src[e];
    }
}

// ---------------- W pre-transpose + bf16 hi/lo split ----------------
// Wt[col][k] = W[k][col] as bf16 hi + lo, so B-fragments are contiguous 16B.
__global__ __launch_bounds__(256) void wconv_k(const float* __restrict__ Wa, const float* __restrict__ Wb,
                                               ushort* __restrict__ Wah, ushort* __restrict__ Wal,
                                               ushort* __restrict__ Wbh, ushort* __restrict__ Wbl) {
    int i = blockIdx.x * 256 + threadIdx.x;
    if (i < DIM * DIM) {
        int col = i >> 7, k = i & 127;
        float a = Wa[k * DIM + col];
        ushort ha = f2bf(a);
        Wah[i] = ha; Wal[i] = f2bf(a - bf2f(ha));
        float b = Wb[k * DIM + col];
        ushort hb = f2bf(b);
        Wbh[i] = hb; Wbl[i] = f2bf(b - bf2f(hb));
    }
}

// ---------------- Fused GCN conv: agg-first + split-bf16 MFMA ----------------
// agg[n] = dinv[n]*(sum_{s in in(n)} dinv[s]*X[s] + dinv[n]*X[n])     (phase 1 -> LDS bf16 hi/lo)
// D      = agg @ W  (3x mfma_16x16x32_bf16: hi*hi + hi*lo + lo*hi)    (phase 2)
// out    = relu(D + bias)  -> global (POOL=false) or per-graph col-sum atomics (POOL=true)
template <bool POOL>
__global__ __launch_bounds__(256) void conv_k(const float* __restrict__ X,
                                              const ushort* __restrict__ Wh, const ushort* __restrict__ Wl,
                                              const float* __restrict__ dinv, const int* __restrict__ offs,
                                              const int* __restrict__ cnt, const int* __restrict__ bucket,
                                              const float* __restrict__ bias,
                                              float* __restrict__ out, float* __restrict__ pooled) {
    __shared__ ushort Ah[64 * DIM];   // 16 KiB, XOR-swizzled
    __shared__ ushort Al[64 * DIM];   // 16 KiB

    int p = blockIdx.x;                       // 2000 blocks
    int blk = (p & 7) * 250 + (p >> 3);       // XCD swizzle: contiguous 250-block chunk per XCD
    int wave = threadIdx.x >> 6, lane = threadIdx.x & 63;
    const int nodeBase = blk * 64;
    const float2* base = (const float2*)X;

    // ---- phase 1: each wave aggregates its 16 rows into LDS (bf16 hi/lo, swizzled) ----
    for (int i = 0; i < 16; ++i) {
        int row = wave * 16 + i;
        int n = __builtin_amdgcn_readfirstlane(nodeBase + row);
        float di = dinv[n];
        int o = __builtin_amdgcn_readfirstlane(offs[n]);
        int m = __builtin_amdgcn_readfirstlane(cnt[n]);

        float ax = 0.f, ay = 0.f;
        int jj = 0;
        for (; jj + 4 <= m; jj += 4) {
            int s0 = bucket[o + jj], s1 = bucket[o + jj + 1];
            int s2 = bucket[o + jj + 2], s3 = bucket[o + jj + 3];
            float w0 = dinv[s0], w1 = dinv[s1], w2 = dinv[s2], w3 = dinv[s3];
            float2 v0 = base[(size_t)s0 * 64 + lane];
            float2 v1 = base[(size_t)s1 * 64 + lane];
            float2 v2 = base[(size_t)s2 * 64 + lane];
            float2 v3 = base[(size_t)s3 * 64 + lane];
            ax += w0 * v0.x + w1 * v1.x + w2 * v2.x + w3 * v3.x;
            ay += w0 * v0.y + w1 * v1.y + w2 * v2.y + w3 * v3.y;
        }
        for (; jj < m; ++jj) {
            int s = bucket[o + jj];
            float w = dinv[s];
            float2 v = base[(size_t)s * 64 + lane];
            ax += w * v.x; ay += w * v.y;
        }
        float2 vs = base[(size_t)n * 64 + lane];
        float gx = di * (ax + di * vs.x);
        float gy = di * (ay + di * vs.y);

        int byte = (row * 256 + lane * 4) ^ ((row & 7) << 4);
        ushort hx = f2bf(gx), hy = f2bf(gy);
        *(ushort2*)((char*)Ah + byte) = make_ushort2(hx, hy);
        *(ushort2*)((char*)Al + byte) = make_ushort2(f2bf(gx - bf2f(hx)), f2bf(gy - bf2f(hy)));
    }
    __syncthreads();

    // ---- phase 2: MFMA. wave owns col-tiles {2w,2w+1}, loops 4 row-strips ----
    int cr = lane & 15, kg = lane >> 4;
    f32x4 acc[2][4];
#pragma unroll
    for (int ct = 0; ct < 2; ++ct)
#pragma unroll
        for (int st = 0; st < 4; ++st) acc[ct][st] = (f32x4)0.f;

#pragma unroll
    for (int t = 0; t < 4; ++t) {
        int kw = t * 32 + kg * 8;
        bf16x8 bh0 = *(const bf16x8*)&Wh[(wave * 32 + cr) * DIM + kw];
        bf16x8 bl0 = *(const bf16x8*)&Wl[(wave * 32 + cr) * DIM + kw];
        bf16x8 bh1 = *(const bf16x8*)&Wh[(wave * 32 + 16 + cr) * DIM + kw];
        bf16x8 bl1 = *(const bf16x8*)&Wl[(wave * 32 + 16 + cr) * DIM + kw];
#pragma unroll
        for (int st = 0; st < 4; ++st) {
            int row = st * 16 + cr;
            int ab = (row * 256 + t * 64 + kg * 16) ^ ((row & 7) << 4);
            bf16x8 ah = *(const bf16x8*)((const char*)Ah + ab);
            bf16x8 al = *(const bf16x8*)((const char*)Al + ab);
            acc[0][st] = __builtin_amdgcn_mfma_f32_16x16x32_bf16(ah, bh0, acc[0][st], 0, 0, 0);
            acc[0][st] = __builtin_amdgcn_mfma_f32_16x16x32_bf16(ah, bl0, acc[0][st], 0, 0, 0);
            acc[0][st] = __builtin_amdgcn_mfma_f32_16x16x32_bf16(al, bh0, acc[0][st], 0, 0, 0);
            acc[1][st] = __builtin_amdgcn_mfma_f32_16x16x32_bf16(ah, bh1, acc[1][st], 0, 0, 0);
            acc[1][st] = __builtin_amdgcn_mfma_f32_16x16x32_bf16(ah, bl1, acc[1][st], 0, 0, 0);
            acc[1][st] = __builtin_amdgcn_mfma_f32_16x16x32_bf16(al, bh1, acc[1][st], 0, 0, 0);
        }
    }

    // ---- epilogue ----
    if (!POOL) {
#pragma unroll
        for (int ct = 0; ct < 2; ++ct) {
            int col = wave * 32 + ct * 16 + cr;
            float bb = bias[col];
#pragma unroll
            for (int st = 0; st < 4; ++st)
#pragma unroll
                for (int rr = 0; rr < 4; ++rr) {
                    int n = nodeBase + st * 16 + kg * 4 + rr;
                    out[(size_t)n * DIM + col] = fmaxf(acc[ct][st][rr] + bb, 0.f);
                }
        }
    } else {
        int g0 = nodeBase / NPG;
        int bnd = (g0 + 1) * NPG;                 // block spans at most graphs g0, g0+1
#pragma unroll
        for (int ct = 0; ct < 2; ++ct) {
            int col = wave * 32 + ct * 16 + cr;
            float bb = bias[col];
            float s1 = 0.f, s2 = 0.f;
#pragma unroll
            for (int st = 0; st < 4; ++st)
#pragma unroll
                for (int rr = 0; rr < 4; ++rr) {
                    int n = nodeBase + st * 16 + kg * 4 + rr;
                    float v = fmaxf(acc[ct][st][rr] + bb, 0.f);
                    if (n < bnd) s1 += v; else s2 += v;
                }
            s1 += __shfl_xor(s1, 16); s1 += __shfl_xor(s1, 32);
            s2 += __shfl_xor(s2, 16); s2 += __shfl_xor(s2, 32);
            if (kg == 0) {
                atomicAdd(&pooled[g0 * DIM + col], s1);
                if (s2 != 0.f) atomicAdd(&pooled[(g0 + 1) * DIM + col], s2);
            }
        }
    }
}

// ---------------- Final MLP head ----------------
__global__ __launch_bounds__(128) void mlp_k(const float* __restrict__ pooled,
                                             const float* __restrict__ W1, const float* __restrict__ b1,
                                             const float* __restrict__ W2, const float* __restrict__ b2,
                                             float* __restrict__ out) {
    int g = blockIdx.x;
    int t = threadIdx.x;
    __shared__ float prow[DIM];
    __shared__ float o1[DIM];
    prow[t] = pooled[g * DIM + t] * (1.0f / (float)KCL);
    __syncthreads();
    float acc = b1[t];
#pragma unroll 8
    for (int d = 0; d < DIM; ++d) acc += prow[d] * W1[d * DIM + t];
    o1[t] = fmaxf(acc, 0.f);
    __syncthreads();
    if (t < CCL) {
        float a = b2[t];
#pragma unroll 8
        for (int cc = 0; cc < DIM; ++cc) a += o1[cc] * W2[cc * CCL + t];
        out[g * CCL + t] = a;
    }
}

extern "C" void kernel_launch(void* const* d_in, const int* in_sizes, int n_in,
                              void* d_out, int out_size, void* d_ws, size_t ws_size,
                              hipStream_t stream) {
    const float* x     = (const float*)d_in[0];
    const int*   ei    = (const int*)d_in[1];      // [2, E]: src then dst
    const float* W_pre = (const float*)d_in[3];
    const float* b_pre = (const float*)d_in[4];
    const float* W_emb = (const float*)d_in[5];
    const float* b_emb = (const float*)d_in[6];
    // W_asn/b_asn provably unused: softmax rows sum to 1, S^T A S unused
    const float* W1    = (const float*)d_in[9];
    const float* b1    = (const float*)d_in[10];
    const float* W2    = (const float*)d_in[11];
    const float* b2    = (const float*)d_in[12];
    float* out = (float*)d_out;

    const int* srcp = ei;
    const int* dstp = ei + EE;

    char* ws = (char*)d_ws;
    size_t off = 0;
    int*    cnt    = (int*)(ws + off);    off += (size_t)NN * 4;
    int*    fill   = (int*)(ws + off);    off += (size_t)NN * 4;
    float*  dinv   = (float*)(ws + off);  off += (size_t)NN * 4;
    int*    offs   = (int*)(ws + off);    off += (size_t)NN * 4;
    float*  pooled = (float*)(ws + off);  off += (size_t)BG * DIM * 4;
    ushort* Wph    = (ushort*)(ws + off); off += (size_t)DIM * DIM * 2;
    ushort* Wpl    = (ushort*)(ws + off); off += (size_t)DIM * DIM * 2;
    ushort* Weh    = (ushort*)(ws + off); off += (size_t)DIM * DIM * 2;
    ushort* Wel    = (ushort*)(ws + off); off += (size_t)DIM * DIM * 2;
    int*    bucket = (int*)(ws + off);    off += (size_t)EE * 4;
    float*  h      = (float*)(ws + off);  off += (size_t)NN * DIM * 4;
    if (ws_size < off) return;

    hipMemsetAsync(cnt, 0, (size_t)NN * 4, stream);
    hipMemsetAsync(fill, 0, (size_t)NN * 4, stream);
    hipMemsetAsync(pooled, 0, (size_t)BG * DIM * 4, stream);

    count_k<<<(EE + 255) / 256, 256, 0, stream>>>(dstp, cnt);
    dinv_k<<<(NN + 255) / 256, 256, 0, stream>>>(cnt, dinv);
    scan_k<<<BG, 256, 0, stream>>>(cnt, offs);
    fill_k<<<(EE + 255) / 256, 256, 0, stream>>>(srcp, dstp, offs, fill, bucket);
    wconv_k<<<(DIM * DIM + 255) / 256, 256, 0, stream>>>(W_pre, W_emb, Wph, Wpl, Weh, Wel);

    // conv1: h = relu(agg(x) @ W_pre + b_pre)
    conv_k<false><<<NN / 64, 256, 0, stream>>>(x, Wph, Wpl, dinv, offs, cnt, bucket, b_pre, h, nullptr);
    // conv2 + fused pooling: pooled[g] += relu(agg(h) @ W_emb + b_emb)  (NE never materialized)
    conv_k<true><<<NN / 64, 256, 0, stream>>>(h, Weh, Wel, dinv, offs, cnt, bucket, b_emb, nullptr, pooled);

    mlp_k<<<BG, 128, 0, stream>>>(pooled, W1, b1, W2, b2, out);
}

// Round 5
// 469.070 us; speedup vs baseline: 2.1330x; 1.1013x over previous
//
#include <hip/hip_runtime.h>
#include <hip/hip_bf16.h>

// Problem constants (match reference setup_inputs)
#define BG   128          // graphs
#define NPG  1000         // nodes per graph
#define EPG  16000        // edges per graph
#define DIM  128          // feature dim
#define KCL  64           // clusters (only appears as 1/K scale)
#define CCL  10           // classes
#define NN   (BG*NPG)     // 128000 nodes
#define EE   (BG*EPG)     // 2048000 edges

typedef __attribute__((ext_vector_type(8))) short bf16x8;
typedef __attribute__((ext_vector_type(4))) float f32x4;

__device__ __forceinline__ ushort f2bf(float x) {       // RNE fp32->bf16
    unsigned u = __float_as_uint(x);
    return (ushort)((u + 0x7fffu + ((u >> 16) & 1u)) >> 16);
}
__device__ __forceinline__ float bf2f(ushort h) { return __uint_as_float(((unsigned)h) << 16); }

// ---------------- CSR build ----------------

__global__ __launch_bounds__(256) void count_k(const int* __restrict__ dst, int* __restrict__ cnt) {
    int e = blockIdx.x * 256 + threadIdx.x;
    if (e < EE) atomicAdd(&cnt[dst[e]], 1);
}

// Per-graph exclusive scan of in-degree counts -> CSR offsets (1 block/graph).
// Also emits dinv[n] = rsqrt(deg+1) and the mutable fill cursor copy.
__global__ __launch_bounds__(256) void scan_k(const int* __restrict__ cnt, int* __restrict__ offs,
                                              int* __restrict__ fillpos, float* __restrict__ dinv) {
    int b = blockIdx.x;
    const int nbase = b * NPG;
    const int ebase = b * EPG;
    __shared__ int sdata[256];
    int running = 0;
    for (int j = 0; j < 4; ++j) {
        int i = j * 256 + threadIdx.x;
        int v = (i < NPG) ? cnt[nbase + i] : 0;
        if (i < NPG) dinv[nbase + i] = rsqrtf((float)(v + 1));
        int x = v;
        sdata[threadIdx.x] = x;
        __syncthreads();
        for (int off = 1; off < 256; off <<= 1) {
            int y = (threadIdx.x >= off) ? sdata[threadIdx.x - off] : 0;
            __syncthreads();
            x += y;
            sdata[threadIdx.x] = x;
            __syncthreads();
        }
        int excl = x - v;
        if (i < NPG) {
            int o = ebase + running + excl;
            offs[nbase + i] = o;
            fillpos[nbase + i] = o;
        }
        int total = sdata[255];
        __syncthreads();
        running += total;
    }
}

__global__ __launch_bounds__(256) void fill_k(const int* __restrict__ src, const int* __restrict__ dst,
                                              int* __restrict__ fillpos, int* __restrict__ bucket) {
    int e = blockIdx.x * 256 + threadIdx.x;
    if (e < EE) {
        int p = atomicAdd(&fillpos[dst[e]], 1);
        bucket[p] = src[e];
    }
}

// ---------------- W pre-transpose + bf16 hi/lo split ----------------
__global__ __launch_bounds__(256) void wconv_k(const float* __restrict__ Wa, const float* __restrict__ Wb,
                                               ushort* __restrict__ Wah, ushort* __restrict__ Wal,
                                               ushort* __restrict__ Wbh, ushort* __restrict__ Wbl) {
    int i = blockIdx.x * 256 + threadIdx.x;
    if (i < DIM * DIM) {
        int col = i >> 7, k = i & 127;
        float a = Wa[k * DIM + col];
        ushort ha = f2bf(a);
        Wah[i] = ha; Wal[i] = f2bf(a - bf2f(ha));
        float b = Wb[k * DIM + col];
        ushort hb = f2bf(b);
        Wbh[i] = hb; Wbl[i] = f2bf(b - bf2f(hb));
    }
}

// ---------------- Fused GCN conv: agg-first + split-bf16 MFMA ----------------
// SCALE_SRC=true  (conv1): agg[n] = di*(sum dinv[s]*X[s]) + di^2*X[n]; out = di*relu(...) [pre-scaled h]
// SCALE_SRC=false (conv2): X rows are pre-scaled: agg[n] = di*(sum X[s] + X[n]); POOL epilogue sums relu.
template <bool SCALE_SRC, bool POOL>
__global__ __launch_bounds__(256, 5) void conv_k(const float* __restrict__ X,
                                              const ushort* __restrict__ Wh, const ushort* __restrict__ Wl,
                                              const float* __restrict__ dinv, const int* __restrict__ offs,
                                              const int* __restrict__ cnt, const int* __restrict__ bucket,
                                              const float* __restrict__ bias,
                                              float* __restrict__ out, float* __restrict__ pooled) {
    __shared__ ushort Ah[64 * DIM];   // 16 KiB, XOR-swizzled
    __shared__ ushort Al[64 * DIM];   // 16 KiB

    int p = blockIdx.x;                       // 2000 blocks
    int blk = (p & 7) * 250 + (p >> 3);       // XCD swizzle: contiguous 250-block chunk per XCD
    int tid = threadIdx.x;
    const int nodeBase = blk * 64;
    const float4* Xv = (const float4*)X;

    // ---- phase 1: 8 half-waves, each aggregates 8 rows (float4 per lane = 16B) ----
    int half = tid >> 5, q = tid & 31;
    for (int i = 0; i < 8; ++i) {
        int row = i * 8 + half;               // row&7 == half -> swizzle spreads halves
        int n = nodeBase + row;
        float di = dinv[n];
        int o = offs[n];
        int m = cnt[n];

        float ax = 0.f, ay = 0.f, az = 0.f, aw = 0.f;
        int jj = 0;
        for (; jj + 4 <= m; jj += 4) {
            int s0 = bucket[o + jj], s1 = bucket[o + jj + 1];
            int s2 = bucket[o + jj + 2], s3 = bucket[o + jj + 3];
            float4 v0 = Xv[(size_t)s0 * 32 + q];
            float4 v1 = Xv[(size_t)s1 * 32 + q];
            float4 v2 = Xv[(size_t)s2 * 32 + q];
            float4 v3 = Xv[(size_t)s3 * 32 + q];
            if (SCALE_SRC) {
                float w0 = dinv[s0], w1 = dinv[s1], w2 = dinv[s2], w3 = dinv[s3];
                ax += w0 * v0.x + w1 * v1.x + w2 * v2.x + w3 * v3.x;
                ay += w0 * v0.y + w1 * v1.y + w2 * v2.y + w3 * v3.y;
                az += w0 * v0.z + w1 * v1.z + w2 * v2.z + w3 * v3.z;
                aw += w0 * v0.w + w1 * v1.w + w2 * v2.w + w3 * v3.w;
            } else {
                ax += (v0.x + v1.x) + (v2.x + v3.x);
                ay += (v0.y + v1.y) + (v2.y + v3.y);
                az += (v0.z + v1.z) + (v2.z + v3.z);
                aw += (v0.w + v1.w) + (v2.w + v3.w);
            }
        }
        for (; jj < m; ++jj) {
            int s = bucket[o + jj];
            float4 v = Xv[(size_t)s * 32 + q];
            if (SCALE_SRC) {
                float w = dinv[s];
                ax += w * v.x; ay += w * v.y; az += w * v.z; aw += w * v.w;
            } else {
                ax += v.x; ay += v.y; az += v.z; aw += v.w;
            }
        }
        float4 vs = Xv[(size_t)n * 32 + q];
        float gx, gy, gz, gw;
        if (SCALE_SRC) {          // conv1: di*(sum + di*self)
            gx = di * (ax + di * vs.x); gy = di * (ay + di * vs.y);
            gz = di * (az + di * vs.z); gw = di * (aw + di * vs.w);
        } else {                  // conv2: di*(sum + self), rows pre-scaled
            gx = di * (ax + vs.x); gy = di * (ay + vs.y);
            gz = di * (az + vs.z); gw = di * (aw + vs.w);
        }

        int byte = (row * 256 + q * 8) ^ ((row & 7) << 4);
        ushort4 hi, lo;
        hi.x = f2bf(gx); lo.x = f2bf(gx - bf2f(hi.x));
        hi.y = f2bf(gy); lo.y = f2bf(gy - bf2f(hi.y));
        hi.z = f2bf(gz); lo.z = f2bf(gz - bf2f(hi.z));
        hi.w = f2bf(gw); lo.w = f2bf(gw - bf2f(hi.w));
        *(ushort4*)((char*)Ah + byte) = hi;
        *(ushort4*)((char*)Al + byte) = lo;
    }
    __syncthreads();

    // ---- phase 2: MFMA. wave owns col-tiles {2w,2w+1}, loops 4 row-strips ----
    int wave = tid >> 6, lane = tid & 63;
    int cr = lane & 15, kg = lane >> 4;
    f32x4 acc[2][4];
#pragma unroll
    for (int ct = 0; ct < 2; ++ct)
#pragma unroll
        for (int st = 0; st < 4; ++st) acc[ct][st] = (f32x4)0.f;

#pragma unroll
    for (int t = 0; t < 4; ++t) {
        int kw = t * 32 + kg * 8;
        bf16x8 bh0 = *(const bf16x8*)&Wh[(wave * 32 + cr) * DIM + kw];
        bf16x8 bl0 = *(const bf16x8*)&Wl[(wave * 32 + cr) * DIM + kw];
        bf16x8 bh1 = *(const bf16x8*)&Wh[(wave * 32 + 16 + cr) * DIM + kw];
        bf16x8 bl1 = *(const bf16x8*)&Wl[(wave * 32 + 16 + cr) * DIM + kw];
#pragma unroll
        for (int st = 0; st < 4; ++st) {
            int row = st * 16 + cr;
            int ab = (row * 256 + t * 64 + kg * 16) ^ ((row & 7) << 4);
            bf16x8 ah = *(const bf16x8*)((const char*)Ah + ab);
            bf16x8 al = *(const bf16x8*)((const char*)Al + ab);
            acc[0][st] = __builtin_amdgcn_mfma_f32_16x16x32_bf16(ah, bh0, acc[0][st], 0, 0, 0);
            acc[0][st] = __builtin_amdgcn_mfma_f32_16x16x32_bf16(ah, bl0, acc[0][st], 0, 0, 0);
            acc[0][st] = __builtin_amdgcn_mfma_f32_16x16x32_bf16(al, bh0, acc[0][st], 0, 0, 0);
            acc[1][st] = __builtin_amdgcn_mfma_f32_16x16x32_bf16(ah, bh1, acc[1][st], 0, 0, 0);
            acc[1][st] = __builtin_amdgcn_mfma_f32_16x16x32_bf16(ah, bl1, acc[1][st], 0, 0, 0);
            acc[1][st] = __builtin_amdgcn_mfma_f32_16x16x32_bf16(al, bh1, acc[1][st], 0, 0, 0);
        }
    }

    // ---- epilogue ----
    if (!POOL) {
        // conv1: write h_scaled = dinv*relu(acc+bias)
#pragma unroll
        for (int ct = 0; ct < 2; ++ct) {
            int col = wave * 32 + ct * 16 + cr;
            float bb = bias[col];
#pragma unroll
            for (int st = 0; st < 4; ++st)
#pragma unroll
                for (int rr = 0; rr < 4; ++rr) {
                    int n = nodeBase + st * 16 + kg * 4 + rr;
                    out[(size_t)n * DIM + col] = dinv[n] * fmaxf(acc[ct][st][rr] + bb, 0.f);
                }
        }
    } else {
        int g0 = nodeBase / NPG;
        int bnd = (g0 + 1) * NPG;                 // block spans at most graphs g0, g0+1
#pragma unroll
        for (int ct = 0; ct < 2; ++ct) {
            int col = wave * 32 + ct * 16 + cr;
            float bb = bias[col];
            float s1 = 0.f, s2 = 0.f;
#pragma unroll
            for (int st = 0; st < 4; ++st)
#pragma unroll
                for (int rr = 0; rr < 4; ++rr) {
                    int n = nodeBase + st * 16 + kg * 4 + rr;
                    float v = fmaxf(acc[ct][st][rr] + bb, 0.f);
                    if (n < bnd) s1 += v; else s2 += v;
                }
            s1 += __shfl_xor(s1, 16); s1 += __shfl_xor(s1, 32);
            s2 += __shfl_xor(s2, 16); s2 += __shfl_xor(s2, 32);
            if (kg == 0) {
                atomicAdd(&pooled[g0 * DIM + col], s1);
                if (s2 != 0.f) atomicAdd(&pooled[(g0 + 1) * DIM + col], s2);
            }
        }
    }
}

// ---------------- Final MLP head ----------------
__global__ __launch_bounds__(128) void mlp_k(const float* __restrict__ pooled,
                                             const float* __restrict__ W1, const float* __restrict__ b1,
                                             const float* __restrict__ W2, const float* __restrict__ b2,
                                             float* __restrict__ out) {
    int g = blockIdx.x;
    int t = threadIdx.x;
    __shared__ float prow[DIM];
    __shared__ float o1[DIM];
    prow[t] = pooled[g * DIM + t] * (1.0f / (float)KCL);
    __syncthreads();
    float acc = b1[t];
#pragma unroll 8
    for (int d = 0; d < DIM; ++d) acc += prow[d] * W1[d * DIM + t];
    o1[t] = fmaxf(acc, 0.f);
    __syncthreads();
    if (t < CCL) {
        float a = b2[t];
#pragma unroll 8
        for (int cc = 0; cc < DIM; ++cc) a += o1[cc] * W2[cc * CCL + t];
        out[g * CCL + t] = a;
    }
}

extern "C" void kernel_launch(void* const* d_in, const int* in_sizes, int n_in,
                              void* d_out, int out_size, void* d_ws, size_t ws_size,
                              hipStream_t stream) {
    const float* x     = (const float*)d_in[0];
    const int*   ei    = (const int*)d_in[1];      // [2, E]: src then dst
    const float* W_pre = (const float*)d_in[3];
    const float* b_pre = (const float*)d_in[4];
    const float* W_emb = (const float*)d_in[5];
    const float* b_emb = (const float*)d_in[6];
    // W_asn/b_asn provably unused: softmax rows sum to 1, S^T A S unused
    const float* W1    = (const float*)d_in[9];
    const float* b1    = (const float*)d_in[10];
    const float* W2    = (const float*)d_in[11];
    const float* b2    = (const float*)d_in[12];
    float* out = (float*)d_out;

    const int* srcp = ei;
    const int* dstp = ei + EE;

    char* ws = (char*)d_ws;
    size_t off = 0;
    int*    cnt     = (int*)(ws + off);    off += (size_t)NN * 4;
    int*    fillpos = (int*)(ws + off);    off += (size_t)NN * 4;
    float*  dinv    = (float*)(ws + off);  off += (size_t)NN * 4;
    int*    offs    = (int*)(ws + off);    off += (size_t)NN * 4;
    float*  pooled  = (float*)(ws + off);  off += (size_t)BG * DIM * 4;
    ushort* Wph     = (ushort*)(ws + off); off += (size_t)DIM * DIM * 2;
    ushort* Wpl     = (ushort*)(ws + off); off += (size_t)DIM * DIM * 2;
    ushort* Weh     = (ushort*)(ws + off); off += (size_t)DIM * DIM * 2;
    ushort* Wel     = (ushort*)(ws + off); off += (size_t)DIM * DIM * 2;
    int*    bucket  = (int*)(ws + off);    off += (size_t)EE * 4;
    float*  h       = (float*)(ws + off);  off += (size_t)NN * DIM * 4;   // h_scaled
    if (ws_size < off) return;

    hipMemsetAsync(cnt, 0, (size_t)NN * 4, stream);
    hipMemsetAsync(pooled, 0, (size_t)BG * DIM * 4, stream);

    count_k<<<(EE + 255) / 256, 256, 0, stream>>>(dstp, cnt);
    scan_k<<<BG, 256, 0, stream>>>(cnt, offs, fillpos, dinv);
    fill_k<<<(EE + 255) / 256, 256, 0, stream>>>(srcp, dstp, fillpos, bucket);
    wconv_k<<<(DIM * DIM + 255) / 256, 256, 0, stream>>>(W_pre, W_emb, Wph, Wpl, Weh, Wel);

    // conv1: h_scaled = dinv * relu(agg(x) @ W_pre + b_pre)
    conv_k<true, false><<<NN / 64, 256, 0, stream>>>(x, Wph, Wpl, dinv, offs, cnt, bucket, b_pre, h, nullptr);
    // conv2 + fused pooling over pre-scaled h
    conv_k<false, true><<<NN / 64, 256, 0, stream>>>(h, Weh, Wel, dinv, offs, cnt, bucket, b_emb, nullptr, pooled);

    mlp_k<<<BG, 128, 0, stream>>>(pooled, W1, b1, W2, b2, out);
}